// Round 16
// baseline (585.510 us; speedup 1.0000x reference)
//
#include <hip/hip_runtime.h>

#define LSZ 64
#define TILE 16

typedef _Float16 f16x8 __attribute__((ext_vector_type(8)));
typedef float    f32x4 __attribute__((ext_vector_type(4)));

// LDS plan (32,000 B, 4 blocks/CU — register-bound, not LDS-bound):
//  s_h1: 400 pos x 40 f16 ([hi x16][lo x16][pad 8]) = 32,000 B
//        ALIASED by s_h2 (f32 position-major [pos][20], 25,920 B) after conv2;
//        conv2 D staged in registers (Cs[6][8]) across the barrier.
//  s_in eliminated (R16): phase 1 reads spin SIGNS direct from global —
//  proven bit-identical in R11 (taps touch exactly the A-sites; mask never
//  observable). R11's regression was the (256,5) spill, NOT this logic.
//
// d_ws (f16): [0) conv2 frags 4x5120   [20480) h1 tables 4x1536
//
// OCCUPANCY RULE (R11/R15): (256,4) is the spill-free max. 5 blocks/CU needs
// <=~96 VGPR but Cs(48)+Bfrags(40) alone is 88 -> structural, don't retry.
// LAYOUT RULE (R13): H1S must be a multiple of 8 f16 (16 B) or b128 A-loads
// split into b64 pairs; 40 is the only size that fits 4 blocks/CU.
// COMPILER RULE (R12/R13): don't fully unroll multi-load bodies (spill).
// NUMERICS RULE (R7): everything feeding a USED logit must stay bit-identical
// (table entries, conv2 split-MFMA order, h2 f32 values, conv3 fmaf ORDER).

__device__ __forceinline__ float fast_tanh(float x) {
    float ax = __builtin_fabsf(x);
    float t  = __builtin_amdgcn_exp2f(ax * -2.885390081777927f);
    float r  = (1.0f - t) * __builtin_amdgcn_rcpf(1.0f + t);
    return __builtin_copysignf(r, x);
}

__device__ __forceinline__ void split_f16(float x, _Float16& hi, _Float16& lo) {
    float h0 = (float)(_Float16)x;
    if (__builtin_fabsf(h0) < 6.104e-5f) h0 = 0.0f;
    hi = (_Float16)h0;
    lo = (_Float16)((x - h0) * 2048.0f);
}

__global__ void prep(const float* __restrict__ W0, const float* __restrict__ B0,
                     const float* __restrict__ W1, _Float16* __restrict__ ws) {
    const int layer = blockIdx.x, tid = threadIdx.x;
    const float* w1g = W1 + layer * 2304;
    _Float16* o2 = ws + layer * 5120;
    for (int e = tid; e < 320; e += 256) {
        int c = e >> 6, lane = e & 63;
        int q = lane >> 4, co = lane & 15;
        #pragma unroll
        for (int j = 0; j < 8; ++j) {
            int k = c * 32 + q * 8 + j;
            float w = (k < 144) ? w1g[k * 16 + co] : 0.0f;
            _Float16 whi, wlo;
            split_f16(w, whi, wlo);
            o2[((c * 2 + 0) * 64 + lane) * 8 + j] = whi;
            o2[((c * 2 + 1) * 64 + lane) * 8 + j] = wlo;
        }
    }
    const float* w0g = W0 + layer * 144;
    const float* b0g = B0 + layer * 16;
    _Float16* ot = ws + 20480 + layer * 1536;
    for (int e = tid; e < 48; e += 256) {
        int sel = (e >= 32);
        int bits = sel ? (e - 32) : e;
        const int wtE[5] = {0, 2, 4, 6, 8};   // taps (0,0)(0,2)(1,1)(2,0)(2,2)
        const int wtO[4] = {1, 3, 5, 7};      // taps (0,1)(1,0)(1,2)(2,1)
        for (int ch = 0; ch < 16; ++ch) {
            float u = b0g[ch];
            if (!sel) {
                #pragma unroll
                for (int t = 0; t < 5; ++t) {
                    float s = ((bits >> t) & 1) ? 1.0f : -1.0f;
                    u = fmaf(s, w0g[wtE[t] * 16 + ch], u);
                }
            } else {
                #pragma unroll
                for (int t = 0; t < 4; ++t) {
                    float s = ((bits >> t) & 1) ? 1.0f : -1.0f;
                    u = fmaf(s, w0g[wtO[t] * 16 + ch], u);
                }
            }
            _Float16 hi, lo;
            split_f16(fast_tanh(u), hi, lo);
            ot[e * 32 + ch]      = hi;
            ot[e * 32 + 16 + ch] = lo;
        }
    }
}

__global__ __launch_bounds__(256, 4)
void discrete_flow_layer(const float* x_in,
                         float* x_out,
                         const _Float16* __restrict__ wfr,
                         const _Float16* __restrict__ tbl,
                         const float* __restrict__ b1g,
                         const float* __restrict__ w2g,
                         const float* __restrict__ b2g,
                         int parityA, int writeA)
{
    __shared__ __align__(16) _Float16 s_h1[400 * 40];   // aliased by s_h2
    float* s_h2 = (float*)s_h1;                          // [pos][20] after barrier

    const int tid  = threadIdx.x;
    const int lane = tid & 63;
    const int wv   = tid >> 6;
    const int tile = blockIdx.x;
    const int b    = blockIdx.y;
    const int r0 = (tile >> 2) * TILE;
    const int c0 = (tile & 3) * TILE;
    const float* xb = x_in + (size_t)b * (LSZ * LSZ);

    // ---- prefetch conv2 weight fragments + bias (global, L2-hot) ----
    f16x8 Bh[5], Bl[5];
    #pragma unroll
    for (int c = 0; c < 5; ++c) {
        Bh[c] = *(const f16x8*)&wfr[((c * 2 + 0) * 64 + lane) * 8];
        Bl[c] = *(const f16x8*)&wfr[((c * 2 + 1) * 64 + lane) * 8];
    }
    const float b1v = b1g[lane & 15];

    // ---- phase 1: h1 by pattern-table lookup; sign bits from GLOBAL ----
    // (R11-proven: bits identical to the masked-LDS path.)
    for (int pp = tid; pp < 400; pp += 256) {
        int g  = (pp >= 200);
        int pi = pp - g * 200;
        int ry = pi / 10;
        int rx = 2 * (pi % 10) + ((ry ^ g) & 1);
        int br = r0 + ry - 3;
        int bc = c0 + rx - 3;
        int sel = g ^ parityA;
        int idx = 0;
        if (sel == 0) {                 // even taps (0,0)(0,2)(1,1)(2,0)(2,2)
            const int kh[5] = {0, 0, 1, 2, 2};
            const int kw[5] = {0, 2, 1, 0, 2};
            #pragma unroll
            for (int t = 0; t < 5; ++t) {
                int gr = (br + kh[t]) & 63, gc = (bc + kw[t]) & 63;
                idx |= (xb[gr * 64 + gc] > 0.0f) << t;
            }
        } else {                        // odd taps (0,1)(1,0)(1,2)(2,1)
            const int kh[4] = {0, 1, 1, 2};
            const int kw[4] = {1, 0, 2, 1};
            #pragma unroll
            for (int t = 0; t < 4; ++t) {
                int gr = (br + kh[t]) & 63, gc = (bc + kw[t]) & 63;
                idx |= (xb[gr * 64 + gc] > 0.0f) << t;
            }
        }
        const f16x8* row = (const f16x8*)&tbl[(sel ? 1024 : 0) + idx * 32];
        f16x8* hp = (f16x8*)&s_h1[(ry * 20 + rx) * 40];
        hp[0] = row[0]; hp[1] = row[1]; hp[2] = row[2]; hp[3] = row[3];
    }
    __syncthreads();

    // ---- phase 2: conv2 MFMA (M=324, N=16, K=144->160); D -> registers ----
    float Cs[6][8];
    {
        const int m0 = lane & 15, q = lane >> 4;
        const int qh = q >> 1, ql = q & 1;
        const int T0 = 0, T1 = 40, T2 = 80, T3 = 800, T4 = 840,
                  T5 = 880, T6 = 1600, T7 = 1640, T8 = 1680, T9 = 1680;
        #pragma unroll
        for (int s = 0; s < 6; ++s) {
            int mt = wv + s * 4;
            if (mt < 21) {
                int m_abs = mt * 16 + m0;
                if (m_abs > 323) m_abs = 323;
                int oy = m_abs / 18, ox = m_abs % 18;
                int abase = (oy * 20 + ox) * 40 + ql * 8;
                f32x4 C0 = {0.f, 0.f, 0.f, 0.f};
                f32x4 C1 = {0.f, 0.f, 0.f, 0.f};
                int off;
                f16x8 A0, A1;
                #define CONV2_STEP(cc, TA, TB)                                        \
                    off = qh ? (TB) : (TA);                                           \
                    A0 = *(const f16x8*)&s_h1[abase + off];                           \
                    A1 = *(const f16x8*)&s_h1[abase + off + 16];                      \
                    C0 = __builtin_amdgcn_mfma_f32_16x16x32_f16(A0, Bh[cc], C0, 0, 0, 0); \
                    C1 = __builtin_amdgcn_mfma_f32_16x16x32_f16(A0, Bl[cc], C1, 0, 0, 0); \
                    C1 = __builtin_amdgcn_mfma_f32_16x16x32_f16(A1, Bh[cc], C1, 0, 0, 0);
                CONV2_STEP(0, T0, T1)
                CONV2_STEP(1, T2, T3)
                CONV2_STEP(2, T4, T5)
                CONV2_STEP(3, T6, T7)
                CONV2_STEP(4, T8, T9)
                #undef CONV2_STEP
                #pragma unroll
                for (int r = 0; r < 4; ++r) { Cs[s][r] = C0[r]; Cs[s][4 + r] = C1[r]; }
            }
        }
    }
    __syncthreads();   // ALL h1 reads complete -> safe to overwrite (h2 alias)

    // ---- phase 3: epilogue, bit-identical h2 values, position-major f32 ----
    {
        const int m0 = lane & 15, q = lane >> 4;
        #pragma unroll
        for (int s = 0; s < 6; ++s) {
            int mt = wv + s * 4;
            if (mt < 21) {
                #pragma unroll
                for (int r = 0; r < 4; ++r) {
                    int m_out = mt * 16 + q * 4 + r;
                    if (m_out < 324) {
                        float val = Cs[s][r] + Cs[s][4 + r] * (1.0f / 2048.0f) + b1v;
                        s_h2[m_out * 20 + m0] = fast_tanh(val);
                    }
                }
            }
        }
    }
    __syncthreads();

    // ---- phase 4: conv3 at B-SITES ONLY (128 threads, 128 used logits) ----
    // Per-site fmaf chain: tap kh-major kw-ascending, ci 0..15 ascending —
    // exact R10/R15 order -> bit-identical.
    if (tid < 128) {
        int ry = tid >> 3;
        int rx = 2 * (tid & 7) + ((ry + parityA + 1) & 1);   // B-parity col
        float acc = b2g[0];
        #pragma unroll
        for (int tap = 0; tap < 9; ++tap) {
            int kh = tap / 3, kw = tap % 3;
            const float* hv = &s_h2[((ry + kh) * 18 + rx + kw) * 20];
            float4 v0 = *(const float4*)&hv[0];
            float4 v1 = *(const float4*)&hv[4];
            float4 v2 = *(const float4*)&hv[8];
            float4 v3 = *(const float4*)&hv[12];
            const float* w = &w2g[tap * 16];
            acc = fmaf(v0.x, w[0],  acc); acc = fmaf(v0.y, w[1],  acc);
            acc = fmaf(v0.z, w[2],  acc); acc = fmaf(v0.w, w[3],  acc);
            acc = fmaf(v1.x, w[4],  acc); acc = fmaf(v1.y, w[5],  acc);
            acc = fmaf(v1.z, w[6],  acc); acc = fmaf(v1.w, w[7],  acc);
            acc = fmaf(v2.x, w[8],  acc); acc = fmaf(v2.y, w[9],  acc);
            acc = fmaf(v2.z, w[10], acc); acc = fmaf(v2.w, w[11], acc);
            acc = fmaf(v3.x, w[12], acc); acc = fmaf(v3.y, w[13], acc);
            acc = fmaf(v3.z, w[14], acc); acc = fmaf(v3.w, w[15], acc);
        }
        int gr = r0 + ry, gc = c0 + rx;
        size_t site = (size_t)b * (LSZ * LSZ) + gr * 64 + gc;
        float xv = x_in[site];
        float m = (acc > 0.0f) ? 1.0f : ((acc < 0.0f) ? -1.0f : 0.0f);
        x_out[site] = xv * m;
    } else if (writeA) {
        // A-site pass-through (layer 0 only)
        int t2 = tid - 128;
        int ry = t2 >> 3;
        int rx = 2 * (t2 & 7) + ((ry + parityA) & 1);        // A-parity col
        int gr = r0 + ry, gc = c0 + rx;
        size_t site = (size_t)b * (LSZ * LSZ) + gr * 64 + gc;
        x_out[site] = x_in[site];
    }
}

extern "C" void kernel_launch(void* const* d_in, const int* in_sizes, int n_in,
                              void* d_out, int out_size, void* d_ws, size_t ws_size,
                              hipStream_t stream) {
    const float* z  = (const float*)d_in[0];
    const float* W0 = (const float*)d_in[1];
    const float* B0 = (const float*)d_in[2];
    const float* W1 = (const float*)d_in[3];
    const float* B1 = (const float*)d_in[4];
    const float* W2 = (const float*)d_in[5];
    const float* B2 = (const float*)d_in[6];
    float* out = (float*)d_out;
    _Float16* ws = (_Float16*)d_ws;   // 53,248 B used

    prep<<<dim3(4), 256, 0, stream>>>(W0, B0, W1, ws);

    dim3 grid(16, 1024);
    for (int layer = 0; layer < 4; ++layer) {
        const float* xin = (layer == 0) ? z : out;
        int writeA = (layer == 0) ? 1 : 0;
        int parityA = layer & 1;
        discrete_flow_layer<<<grid, 256, 0, stream>>>(
            xin, out,
            ws + layer * 5120,
            ws + 20480 + layer * 1536,
            B1 + layer * 16,
            W2 + layer * 144,
            B2 + layer * 1,
            parityA, writeA);
    }
}

// Round 17
// 570.750 us; speedup vs baseline: 1.0259x; 1.0259x over previous
//
#include <hip/hip_runtime.h>

#define LSZ 64
#define TILE 16

typedef _Float16 f16x8 __attribute__((ext_vector_type(8)));
typedef float    f32x4 __attribute__((ext_vector_type(4)));

// LDS plan (33,936 B -> 4 blocks/CU):  [R15 structure, phases 0-3 verbatim]
//  s_h1: 400 pos x 40 f16 ([hi x16][lo x16][pad 8]) = 32,000 B
//        ALIASED by s_h2 (f32 position-major [pos][20], 25,920 B) after conv2;
//        conv2 D staged in registers (Cs[6][8]) across the barrier.
//  s_in: 484 f32 = 1,936 B (R16 showed global-sign reads regress — keep staging)
//
// d_ws (f16): [0) conv2 frags 4x5120   [20480) h1 tables 4x1536
//
// OCCUPANCY RULE (R11/R15): (256,4) is the spill-free max (structural).
// COMPILER RULE (R12/R13): don't fully unroll multi-load bodies (spill).
// LAYOUT RULE (R13): h1/h2 strides must keep 16 B alignment for b128.
// NUMERICS RULE (R7): everything feeding a USED logit stays bit-identical.
// R17 delta vs R15: phase-4 lane map row-interleaved so consecutive lanes'
// h2 positions step ODD -> start banks cover all 8 cosets -> conv3 b128
// reads at the 8-touch/bank minimum (R15 map was 2x over minimum).

__device__ __forceinline__ float fast_tanh(float x) {
    float ax = __builtin_fabsf(x);
    float t  = __builtin_amdgcn_exp2f(ax * -2.885390081777927f);
    float r  = (1.0f - t) * __builtin_amdgcn_rcpf(1.0f + t);
    return __builtin_copysignf(r, x);
}

__device__ __forceinline__ void split_f16(float x, _Float16& hi, _Float16& lo) {
    float h0 = (float)(_Float16)x;
    if (__builtin_fabsf(h0) < 6.104e-5f) h0 = 0.0f;
    hi = (_Float16)h0;
    lo = (_Float16)((x - h0) * 2048.0f);
}

__global__ void prep(const float* __restrict__ W0, const float* __restrict__ B0,
                     const float* __restrict__ W1, _Float16* __restrict__ ws) {
    const int layer = blockIdx.x, tid = threadIdx.x;
    const float* w1g = W1 + layer * 2304;
    _Float16* o2 = ws + layer * 5120;
    for (int e = tid; e < 320; e += 256) {
        int c = e >> 6, lane = e & 63;
        int q = lane >> 4, co = lane & 15;
        #pragma unroll
        for (int j = 0; j < 8; ++j) {
            int k = c * 32 + q * 8 + j;
            float w = (k < 144) ? w1g[k * 16 + co] : 0.0f;
            _Float16 whi, wlo;
            split_f16(w, whi, wlo);
            o2[((c * 2 + 0) * 64 + lane) * 8 + j] = whi;
            o2[((c * 2 + 1) * 64 + lane) * 8 + j] = wlo;
        }
    }
    const float* w0g = W0 + layer * 144;
    const float* b0g = B0 + layer * 16;
    _Float16* ot = ws + 20480 + layer * 1536;
    for (int e = tid; e < 48; e += 256) {
        int sel = (e >= 32);
        int bits = sel ? (e - 32) : e;
        const int wtE[5] = {0, 2, 4, 6, 8};   // taps (0,0)(0,2)(1,1)(2,0)(2,2)
        const int wtO[4] = {1, 3, 5, 7};      // taps (0,1)(1,0)(1,2)(2,1)
        for (int ch = 0; ch < 16; ++ch) {
            float u = b0g[ch];
            if (!sel) {
                #pragma unroll
                for (int t = 0; t < 5; ++t) {
                    float s = ((bits >> t) & 1) ? 1.0f : -1.0f;
                    u = fmaf(s, w0g[wtE[t] * 16 + ch], u);
                }
            } else {
                #pragma unroll
                for (int t = 0; t < 4; ++t) {
                    float s = ((bits >> t) & 1) ? 1.0f : -1.0f;
                    u = fmaf(s, w0g[wtO[t] * 16 + ch], u);
                }
            }
            _Float16 hi, lo;
            split_f16(fast_tanh(u), hi, lo);
            ot[e * 32 + ch]      = hi;
            ot[e * 32 + 16 + ch] = lo;
        }
    }
}

__global__ __launch_bounds__(256, 4)
void discrete_flow_layer(const float* x_in,
                         float* x_out,
                         const _Float16* __restrict__ wfr,
                         const _Float16* __restrict__ tbl,
                         const float* __restrict__ b1g,
                         const float* __restrict__ w2g,
                         const float* __restrict__ b2g,
                         int parityA, int writeA)
{
    __shared__ __align__(16) _Float16 s_h1[400 * 40];   // aliased by s_h2
    __shared__ __align__(16) float    s_in[484];
    float* s_h2 = (float*)s_h1;                          // [pos][20] after barrier

    const int tid  = threadIdx.x;
    const int lane = tid & 63;
    const int wv   = tid >> 6;
    const int tile = blockIdx.x;
    const int b    = blockIdx.y;
    const int r0 = (tile >> 2) * TILE;
    const int c0 = (tile & 3) * TILE;
    const float* xb = x_in + (size_t)b * (LSZ * LSZ);

    // ---- prefetch conv2 weight fragments + bias (global, L2-hot) ----
    f16x8 Bh[5], Bl[5];
    #pragma unroll
    for (int c = 0; c < 5; ++c) {
        Bh[c] = *(const f16x8*)&wfr[((c * 2 + 0) * 64 + lane) * 8];
        Bl[c] = *(const f16x8*)&wfr[((c * 2 + 1) * 64 + lane) * 8];
    }
    const float b1v = b1g[lane & 15];

    // ---- phase 0: stage masked input tile (22x22, wrap) ----
    for (int idx = tid; idx < 484; idx += 256) {
        int r = idx / 22, c = idx % 22;
        int gr = (r0 + r - 3) & 63;
        int gc = (c0 + c - 3) & 63;
        float v = xb[gr * 64 + gc];
        s_in[idx] = (((gr + gc) & 1) == parityA) ? v : 0.0f;
    }
    __syncthreads();

    // ---- phase 1: h1 by pattern-table lookup ----
    for (int pp = tid; pp < 400; pp += 256) {
        int g  = (pp >= 200);
        int pi = pp - g * 200;
        int ry = pi / 10;
        int rx = 2 * (pi % 10) + ((ry ^ g) & 1);
        int base = ry * 22 + rx;
        int sel = g ^ parityA;
        int idx = 0;
        if (sel == 0) {                        // even-sum taps
            const int off[5] = {0, 2, 23, 44, 46};
            #pragma unroll
            for (int t = 0; t < 5; ++t)
                idx |= (s_in[base + off[t]] > 0.0f) << t;
        } else {                               // odd-sum taps
            const int off[4] = {1, 22, 24, 45};
            #pragma unroll
            for (int t = 0; t < 4; ++t)
                idx |= (s_in[base + off[t]] > 0.0f) << t;
        }
        const f16x8* row = (const f16x8*)&tbl[(sel ? 1024 : 0) + idx * 32];
        f16x8* hp = (f16x8*)&s_h1[(ry * 20 + rx) * 40];
        hp[0] = row[0]; hp[1] = row[1]; hp[2] = row[2]; hp[3] = row[3];
    }
    __syncthreads();

    // ---- phase 2: conv2 MFMA (M=324, N=16, K=144->160); D -> registers ----
    float Cs[6][8];
    {
        const int m0 = lane & 15, q = lane >> 4;
        const int qh = q >> 1, ql = q & 1;
        const int T0 = 0, T1 = 40, T2 = 80, T3 = 800, T4 = 840,
                  T5 = 880, T6 = 1600, T7 = 1640, T8 = 1680, T9 = 1680;
        #pragma unroll
        for (int s = 0; s < 6; ++s) {
            int mt = wv + s * 4;
            if (mt < 21) {
                int m_abs = mt * 16 + m0;
                if (m_abs > 323) m_abs = 323;
                int oy = m_abs / 18, ox = m_abs % 18;
                int abase = (oy * 20 + ox) * 40 + ql * 8;
                f32x4 C0 = {0.f, 0.f, 0.f, 0.f};
                f32x4 C1 = {0.f, 0.f, 0.f, 0.f};
                int off;
                f16x8 A0, A1;
                #define CONV2_STEP(cc, TA, TB)                                        \
                    off = qh ? (TB) : (TA);                                           \
                    A0 = *(const f16x8*)&s_h1[abase + off];                           \
                    A1 = *(const f16x8*)&s_h1[abase + off + 16];                      \
                    C0 = __builtin_amdgcn_mfma_f32_16x16x32_f16(A0, Bh[cc], C0, 0, 0, 0); \
                    C1 = __builtin_amdgcn_mfma_f32_16x16x32_f16(A0, Bl[cc], C1, 0, 0, 0); \
                    C1 = __builtin_amdgcn_mfma_f32_16x16x32_f16(A1, Bh[cc], C1, 0, 0, 0);
                CONV2_STEP(0, T0, T1)
                CONV2_STEP(1, T2, T3)
                CONV2_STEP(2, T4, T5)
                CONV2_STEP(3, T6, T7)
                CONV2_STEP(4, T8, T9)
                #undef CONV2_STEP
                #pragma unroll
                for (int r = 0; r < 4; ++r) { Cs[s][r] = C0[r]; Cs[s][4 + r] = C1[r]; }
            }
        }
    }
    __syncthreads();   // ALL h1 reads complete -> safe to overwrite (h2 alias)

    // ---- phase 3: epilogue, bit-identical h2 values, position-major f32 ----
    {
        const int m0 = lane & 15, q = lane >> 4;
        #pragma unroll
        for (int s = 0; s < 6; ++s) {
            int mt = wv + s * 4;
            if (mt < 21) {
                #pragma unroll
                for (int r = 0; r < 4; ++r) {
                    int m_out = mt * 16 + q * 4 + r;
                    if (m_out < 324) {
                        float val = Cs[s][r] + Cs[s][4 + r] * (1.0f / 2048.0f) + b1v;
                        s_h2[m_out * 20 + m0] = fast_tanh(val);
                    }
                }
            }
        }
    }
    __syncthreads();

    // ---- phase 4: conv3 at B-SITES ONLY, row-interleaved lane map ----
    // Consecutive lanes alternate adjacent rows -> odd p-steps -> start banks
    // cover all 8 cosets -> conv3 b128 reads at the 8-touch/bank minimum.
    // Per-site fmaf chain: tap kh-major kw-ascending, ci 0..15 ascending —
    // exact R15 order -> bit-identical logits.
    if (tid < 128) {
        int pr = tid >> 4;                     // row pair 0..7
        int j4 = tid & 15;
        int ry = pr * 2 + (j4 & 1);
        int k  = j4 >> 1;                      // 0..7
        int rx = 2 * k + ((ry + parityA + 1) & 1);   // B-parity col
        float acc = b2g[0];
        #pragma unroll
        for (int tap = 0; tap < 9; ++tap) {
            int kh = tap / 3, kw = tap % 3;
            const float* hv = &s_h2[((ry + kh) * 18 + rx + kw) * 20];
            float4 v0 = *(const float4*)&hv[0];
            float4 v1 = *(const float4*)&hv[4];
            float4 v2 = *(const float4*)&hv[8];
            float4 v3 = *(const float4*)&hv[12];
            const float* w = &w2g[tap * 16];
            acc = fmaf(v0.x, w[0],  acc); acc = fmaf(v0.y, w[1],  acc);
            acc = fmaf(v0.z, w[2],  acc); acc = fmaf(v0.w, w[3],  acc);
            acc = fmaf(v1.x, w[4],  acc); acc = fmaf(v1.y, w[5],  acc);
            acc = fmaf(v1.z, w[6],  acc); acc = fmaf(v1.w, w[7],  acc);
            acc = fmaf(v2.x, w[8],  acc); acc = fmaf(v2.y, w[9],  acc);
            acc = fmaf(v2.z, w[10], acc); acc = fmaf(v2.w, w[11], acc);
            acc = fmaf(v3.x, w[12], acc); acc = fmaf(v3.y, w[13], acc);
            acc = fmaf(v3.z, w[14], acc); acc = fmaf(v3.w, w[15], acc);
        }
        int gr = r0 + ry, gc = c0 + rx;
        size_t site = (size_t)b * (LSZ * LSZ) + gr * 64 + gc;
        float xv = x_in[site];
        float m = (acc > 0.0f) ? 1.0f : ((acc < 0.0f) ? -1.0f : 0.0f);
        x_out[site] = xv * m;
    } else if (writeA) {
        // A-site pass-through (layer 0 only)
        int t2 = tid - 128;
        int ry = t2 >> 3;
        int rx = 2 * (t2 & 7) + ((ry + parityA) & 1);        // A-parity col
        int gr = r0 + ry, gc = c0 + rx;
        size_t site = (size_t)b * (LSZ * LSZ) + gr * 64 + gc;
        x_out[site] = x_in[site];
    }
}

extern "C" void kernel_launch(void* const* d_in, const int* in_sizes, int n_in,
                              void* d_out, int out_size, void* d_ws, size_t ws_size,
                              hipStream_t stream) {
    const float* z  = (const float*)d_in[0];
    const float* W0 = (const float*)d_in[1];
    const float* B0 = (const float*)d_in[2];
    const float* W1 = (const float*)d_in[3];
    const float* B1 = (const float*)d_in[4];
    const float* W2 = (const float*)d_in[5];
    const float* B2 = (const float*)d_in[6];
    float* out = (float*)d_out;
    _Float16* ws = (_Float16*)d_ws;   // 53,248 B used

    prep<<<dim3(4), 256, 0, stream>>>(W0, B0, W1, ws);

    dim3 grid(16, 1024);
    for (int layer = 0; layer < 4; ++layer) {
        const float* xin = (layer == 0) ? z : out;
        int writeA = (layer == 0) ? 1 : 0;
        int parityA = layer & 1;
        discrete_flow_layer<<<grid, 256, 0, stream>>>(
            xin, out,
            ws + layer * 5120,
            ws + 20480 + layer * 1536,
            B1 + layer * 16,
            W2 + layer * 144,
            B2 + layer * 1,
            parityA, writeA);
    }
}